// Round 1
// 125.440 us; speedup vs baseline: 1.0079x; 1.0079x over previous
//
#include <hip/hip_runtime.h>

// Problem constants
#define B_  64
#define L_  2048
#define C_  64
#define K_  8
#define F_  24
#define D_  32   // K_ + F_
#define H_  64

// Output layout (flat floats): x_aug [B*L*C] | prob [B*K] | intensity [B*K] | selected_idx [B]
#define XAUG_N   (B_ * L_ * C_)          // 8388608
#define PROB_OFF (XAUG_N)
#define INT_OFF  (PROB_OFF + B_ * K_)
#define SEL_OFF  (INT_OFF + B_ * K_)

#define VEC_PER_BATCH   (L_ * C_ / 4)    // 32768 float4 per batch row
#define BLOCKS_PER_B    16               // 16 blocks per batch
#define VEC_PER_BLOCK   (VEC_PER_BATCH / BLOCKS_PER_B)   // 2048
#define ITERS           (VEC_PER_BLOCK / 256)            // 8 float4 per thread

__device__ __forceinline__ float softplus_f(float v) {
    return fmaxf(v, 0.f) + log1pf(expf(-fabsf(v)));
}

// ---------------------------------------------------------------------------
// One full wave (64 lanes) computes a 32->64->64->8 MLP entirely in registers.
// Layer activations live one-per-lane; cross-lane gathers via __shfl
// (compile-time source lane -> v_readlane), final 8 outputs via 6-level
// shfl_xor butterfly so EVERY lane ends with all 8 outputs.
// ---------------------------------------------------------------------------
__device__ __forceinline__ void wave_mlp(
    int lane, const float* in_v,
    const float* __restrict__ W1, const float* __restrict__ b1,
    const float* __restrict__ W2, const float* __restrict__ b2,
    const float* __restrict__ W3, const float* __restrict__ b3,
    float* out8)
{
    float acc = b1[lane];
    #pragma unroll
    for (int d = 0; d < D_; ++d) acc = fmaf(in_v[d], W1[d * H_ + lane], acc);
    const float a1 = fmaxf(acc, 0.f);

    acc = b2[lane];
    #pragma unroll
    for (int d = 0; d < H_; ++d) acc = fmaf(__shfl(a1, d), W2[d * H_ + lane], acc);
    const float a2 = fmaxf(acc, 0.f);

    // lane's row of W3: contribution a2 * W3[lane][k], reduced over lanes.
    const float4 w3a = *(const float4*)(W3 + lane * K_);
    const float4 w3b = *(const float4*)(W3 + lane * K_ + 4);
    float pr[K_] = { a2 * w3a.x, a2 * w3a.y, a2 * w3a.z, a2 * w3a.w,
                     a2 * w3b.x, a2 * w3b.y, a2 * w3b.z, a2 * w3b.w };
    #pragma unroll
    for (int k = 0; k < K_; ++k) {
        float p = pr[k];
        #pragma unroll
        for (int off = 32; off > 0; off >>= 1) p += __shfl_xor(p, off);
        out8[k] = p + b3[k];
    }
}

// ---------------------------------------------------------------------------
// Single fused kernel, 1024 blocks (16/batch) x 256 threads, ONE barrier.
//   waves 2,3 : prefetch all 8 float4 of x immediately (stream starts at t=0)
//   wave 0    : prob-MLP (shuffle-only, no barriers)      -> s_log[0..7]
//   wave 1    : intensity-MLP (concurrent with wave 0)    -> s_log[8..15]
//   __syncthreads()  (the only barrier)
//   all threads: redundant finalize (softmax/softplus/gumbel/argmax ->
//                kind,p0,p1), then apply + store.
// Time reversal (kind 3) reads LINEAR and stores MIRRORED, so the prefetch
// is valid for every transform:
//   kind 0: y = p0*x + p1          (ops 0,1,2,3,5)
//   kind 1: y = p0*tanh(p1*x)      (op 4)
//   kind 2: y = p0*x + p1*sin(x)   (op 6)
//   kind 3: y[L-1-l] = p0*x[l]     (op 7)
// No inter-block dependency of any kind (G16-safe).
// ---------------------------------------------------------------------------
__global__ void __launch_bounds__(256, 4) fused_kernel(
    const float* __restrict__ x,
    const float* __restrict__ prev_prob, const float* __restrict__ features,
    const float* __restrict__ gumbel,    const float* __restrict__ log_temp,
    const float* __restrict__ pW1, const float* __restrict__ pb1,
    const float* __restrict__ pW2, const float* __restrict__ pb2,
    const float* __restrict__ pW3, const float* __restrict__ pb3,
    const float* __restrict__ iW1, const float* __restrict__ ib1,
    const float* __restrict__ iW2, const float* __restrict__ ib2,
    const float* __restrict__ iW3, const float* __restrict__ ib3,
    float* __restrict__ out)
{
    const int b    = blockIdx.x >> 4;                 // batch row
    const int blk  = blockIdx.x & (BLOCKS_PER_B - 1); // slab within batch
    const int tid  = threadIdx.x;
    const int wave = tid >> 6;
    const int lane = tid & 63;

    __shared__ float s_log[2 * K_];

    const int base = blk * VEC_PER_BLOCK + tid;
    const float4* xb = (const float4*)x + (size_t)b * VEC_PER_BATCH;
    float4*       ob = (float4*)out + (size_t)b * VEC_PER_BATCH;

    float4 xv[ITERS];
    if (wave >= 2) {
        // streaming waves: issue all loads right away, overlap with head
        #pragma unroll
        for (int i = 0; i < ITERS; ++i) xv[i] = xb[base + i * 256];
    } else {
        // head inputs are block-uniform -> scalar loads
        float in_v[D_];
        #pragma unroll
        for (int d = 0; d < K_; ++d) in_v[d] = prev_prob[b * K_ + d];
        #pragma unroll
        for (int d = 0; d < F_; ++d) in_v[K_ + d] = features[b * F_ + d];

        const bool w0 = (wave == 0);
        float lg[K_];
        wave_mlp(lane, in_v,
                 w0 ? pW1 : iW1, w0 ? pb1 : ib1,
                 w0 ? pW2 : iW2, w0 ? pb2 : ib2,
                 w0 ? pW3 : iW3, w0 ? pb3 : ib3, lg);

        if (lane == 0) {
            #pragma unroll
            for (int k = 0; k < K_; ++k) s_log[wave * K_ + k] = lg[k];
        }
        // keep the compiler from hoisting these loads above the head
        // (vmcnt is issue-ordered: waiting on head weight loads would
        //  otherwise also drain these)
        __builtin_amdgcn_sched_barrier(0);
        #pragma unroll
        for (int i = 0; i < ITERS; ++i) xv[i] = xb[base + i * 256];
    }

    __syncthreads();   // the only barrier

    // ---- redundant finalize in every thread (all inputs block-uniform) ----
    float plog[K_], ilog[K_];
    #pragma unroll
    for (int k = 0; k < K_; ++k) { plog[k] = s_log[k]; ilog[k] = s_log[K_ + k]; }

    float m = plog[0];
    #pragma unroll
    for (int k = 1; k < K_; ++k) m = fmaxf(m, plog[k]);
    float e[K_], se = 0.f;
    #pragma unroll
    for (int k = 0; k < K_; ++k) { e[k] = expf(plog[k] - m); se += e[k]; }

    float inten[K_];
    #pragma unroll
    for (int k = 0; k < K_; ++k) inten[k] = softplus_f(ilog[k]);

    float tau = expf(log_temp[0]);
    tau = fminf(fmaxf(tau, 0.01f), 10.0f);
    float z[K_], m2 = -3.4e38f;
    #pragma unroll
    for (int k = 0; k < K_; ++k) {
        z[k] = (plog[k] + gumbel[b * K_ + k]) / tau;
        m2 = fmaxf(m2, z[k]);
    }
    float se2 = 0.f;
    #pragma unroll
    for (int k = 0; k < K_; ++k) { z[k] = expf(z[k] - m2); se2 += z[k]; }
    int idx = 0; float best = z[0];
    #pragma unroll
    for (int k = 1; k < K_; ++k) { if (z[k] > best) { best = z[k]; idx = k; } }

    const float ys  = best / se2;
    const float sel = (1.0f + ys) - ys;   // straight-through value

    if (blk == 0 && tid == 0) {
        #pragma unroll
        for (int k = 0; k < K_; ++k) out[PROB_OFF + b * K_ + k] = e[k] / se;
        #pragma unroll
        for (int k = 0; k < K_; ++k) out[INT_OFF + b * K_ + k] = inten[k];
        out[SEL_OFF + b] = (float)idx;
    }

    // select inten[idx] without runtime-indexing a register array (rule #20)
    float t = inten[0];
    #pragma unroll
    for (int k = 1; k < K_; ++k) t = (idx == k) ? inten[k] : t;

    int kind; float p0, p1 = 0.f;
    switch (idx) {
        case 0: kind = 0; p0 = sel;                  break;
        case 1: kind = 0; p0 = sel * (1.f + t);      break;
        case 2: kind = 0; p0 = sel; p1 = sel * t;    break;
        case 3: kind = 0; p0 = sel * (1.f - t);      break;
        case 4: kind = 1; p0 = sel; p1 = 1.f + t;    break;
        case 5: kind = 0; p0 = sel * expf(-t);       break;
        case 6: kind = 2; p0 = sel; p1 = sel * t;    break;
        default: kind = 3; p0 = sel;                 break;
    }

    // ---- apply + store (loads already in registers) ----
    if (kind == 0) {
        #pragma unroll
        for (int i = 0; i < ITERS; ++i) {
            float4 r;
            r.x = fmaf(p0, xv[i].x, p1);
            r.y = fmaf(p0, xv[i].y, p1);
            r.z = fmaf(p0, xv[i].z, p1);
            r.w = fmaf(p0, xv[i].w, p1);
            ob[base + i * 256] = r;
        }
    } else if (kind == 1) {
        #pragma unroll
        for (int i = 0; i < ITERS; ++i) {
            float4 r;
            r.x = p0 * tanhf(p1 * xv[i].x);
            r.y = p0 * tanhf(p1 * xv[i].y);
            r.z = p0 * tanhf(p1 * xv[i].z);
            r.w = p0 * tanhf(p1 * xv[i].w);
            ob[base + i * 256] = r;
        }
    } else if (kind == 2) {
        #pragma unroll
        for (int i = 0; i < ITERS; ++i) {
            float4 r;
            r.x = fmaf(p0, xv[i].x, p1 * sinf(xv[i].x));
            r.y = fmaf(p0, xv[i].y, p1 * sinf(xv[i].y));
            r.z = fmaf(p0, xv[i].z, p1 * sinf(xv[i].z));
            r.w = fmaf(p0, xv[i].w, p1 * sinf(xv[i].w));
            ob[base + i * 256] = r;
        }
    } else {
        // time reversal: read linear, store mirrored.
        // out[(L-1-l)*16 + c] = p0 * x[l*16 + c]; slabs mirror block-exclusively.
        #pragma unroll
        for (int i = 0; i < ITERS; ++i) {
            const int v = base + i * 256;
            const int l = v >> 4, c = v & 15;
            float4 r;
            r.x = p0 * xv[i].x; r.y = p0 * xv[i].y;
            r.z = p0 * xv[i].z; r.w = p0 * xv[i].w;
            ob[(L_ - 1 - l) * 16 + c] = r;
        }
    }
}

extern "C" void kernel_launch(void* const* d_in, const int* in_sizes, int n_in,
                              void* d_out, int out_size, void* d_ws, size_t ws_size,
                              hipStream_t stream) {
    const float* x         = (const float*)d_in[0];
    const float* prev_prob = (const float*)d_in[1];
    const float* features  = (const float*)d_in[2];
    const float* gumbel    = (const float*)d_in[3];
    const float* log_temp  = (const float*)d_in[4];
    const float* pW1 = (const float*)d_in[5];
    const float* pb1 = (const float*)d_in[6];
    const float* pW2 = (const float*)d_in[7];
    const float* pb2 = (const float*)d_in[8];
    const float* pW3 = (const float*)d_in[9];
    const float* pb3 = (const float*)d_in[10];
    const float* iW1 = (const float*)d_in[11];
    const float* ib1 = (const float*)d_in[12];
    const float* iW2 = (const float*)d_in[13];
    const float* ib2 = (const float*)d_in[14];
    const float* iW3 = (const float*)d_in[15];
    const float* ib3 = (const float*)d_in[16];

    float* out = (float*)d_out;

    hipLaunchKernelGGL(fused_kernel, dim3(B_ * BLOCKS_PER_B), dim3(256), 0, stream,
                       x, prev_prob, features, gumbel, log_temp,
                       pW1, pb1, pW2, pb2, pW3, pb3,
                       iW1, ib1, iW2, ib2, iW3, ib3,
                       out);
}